// Round 2
// 244.786 us; speedup vs baseline: 1.0703x; 1.0703x over previous
//
#include <hip/hip_runtime.h>

// QuantumRNNCell v4.1: single fused kernel (v4 + nontemporal-store type fix).
//
//   Sim: ONE WAVE per batch element, lane l holds amplitude of basis state l
//   (wire w <-> bit (5-w), pennylane MSB order). 1q gates = 2x shfl_xor + FMA,
//   CNOT ring = one shfl with a precomputed GF(2)-linear source lane,
//   PauliZ expvals = 6-stage Walsh-Hadamard butterfly (q[j] at lane 32>>j).
//   => 32768 waves (32/SIMD) instead of v3's 512 waves (0.5/SIMD).
//
//   Epilogue fused in the same block: each 256-thread block owns 4 rows
//   (one per wave): rows bid + k*gridDim. hx/fc_w loads are issued BEFORE the
//   sim phase so the ~800-cycle sim VALU hides HBM latency; out uses
//   nontemporal stores so hx stays L3-resident across graph replays.
//
// Fixed problem shape: B = 32768, H = 1024 (256 float4 per row).

#define NQ 6

// native vector type for nontemporal store (HIP float4 is a class -> rejected)
typedef float floatx4 __attribute__((ext_vector_type(4)));

__global__ __launch_bounds__(256, 4) void qrnn_fused_kernel(
    const float* __restrict__ x,     // (B, 6)
    const float* __restrict__ hx,    // (B, H)
    const float* __restrict__ qw,    // (3, 6)
    const float* __restrict__ fc_w,  // (H, 6)
    const float* __restrict__ fc_b,  // (H,)
    float* __restrict__ out)         // (B, H)
{
    const int tid = threadIdx.x;
    const int l   = tid & 63;        // lane = basis state
    const int wv  = tid >> 6;        // wave 0..3 = row within block
    const int bid = blockIdx.x;
    const int G   = gridDim.x;       // B/4

    __shared__ float q6s[4][6];

    // ---- phase 0: issue ALL epilogue global loads up front ----
    const float4* hx4 = (const float4*)hx;
    float4 hv0 = hx4[(size_t)(bid + 0 * G) * 256 + tid];
    float4 hv1 = hx4[(size_t)(bid + 1 * G) * 256 + tid];
    float4 hv2 = hx4[(size_t)(bid + 2 * G) * 256 + tid];
    float4 hv3 = hx4[(size_t)(bid + 3 * G) * 256 + tid];
    const float4* w4 = (const float4*)fc_w;     // 6 float4 = fc_w rows 4t..4t+3
    const int wb = tid * 6;
    float4 a0 = w4[wb + 0], a1 = w4[wb + 1], a2 = w4[wb + 2];
    float4 a3 = w4[wb + 3], a4 = w4[wb + 4], a5 = w4[wb + 5];
    float4 bv = ((const float4*)fc_b)[tid];

    // ---- phase 1: wave-parallel quantum sim ----
    const int b = bid + wv * G;      // this wave's batch row

    // one sincos per wave: lanes 0-5 = x angles, lanes 6-23 = qw angles
    float ang = 0.f;
    if (l < 6)        ang = x[(size_t)b * NQ + l];
    else if (l < 24)  ang = qw[l - 6];
    float sa, ca;
    __sincosf(ang * 0.5f, &sa, &ca);

    float cx[6], sx[6];
    #pragma unroll
    for (int i = 0; i < 6; ++i) { cx[i] = __shfl(ca, i); sx[i] = __shfl(sa, i); }

    float re = (l == 0) ? 1.f : 0.f;
    float im = 0.f;

    // encoding: RX(x[i]), RY(x[i+1]), RZ(x[i+2]) on wire i (bit 5-i)
    #pragma unroll
    for (int w = 0; w < 6; ++w) {
        const int m = 1 << (5 - w);
        const float sgn = (l & m) ? 1.f : -1.f;
        // RX: a' = c*a - i*s*partner  -> nr = c*r + s*pi ; ni = c*i - s*pr
        float pr = __shfl_xor(re, m), pi = __shfl_xor(im, m);
        float c = cx[w], s = sx[w];
        float nr = c * re + s * pi;
        float ni = c * im - s * pr;
        re = nr; im = ni;
        // RY: bit0: c*a0 - s*a1 ; bit1: s*a0 + c*a1  -> sign = +1 iff bit set
        pr = __shfl_xor(re, m); pi = __shfl_xor(im, m);
        c = cx[(w + 1) % 6]; s = sx[(w + 1) % 6] * sgn;
        nr = c * re + s * pr;
        ni = c * im + s * pi;
        re = nr; im = ni;
        // RZ: *= e^{-+ i t/2}: bit0: nr=c*r+s*i, ni=c*i-s*r ; bit1 flips s
        c = cx[(w + 2) % 6];
        const float sg = (l & m) ? -sx[(w + 2) % 6] : sx[(w + 2) % 6];
        nr = c * re + sg * im;
        ni = c * im - sg * re;
        re = nr; im = ni;
    }

    // CNOT-ring composed permutation: new[l] = old[src], src GF(2)-linear in l
    // (same loop as v3's harness-verified make_perm, applied per-lane)
    int src = l;
    #pragma unroll
    for (int q = 5; q >= 0; --q) {
        const int cb = 5 - q, tb = 5 - ((q + 1) % 6);
        src ^= ((src >> cb) & 1) << tb;
    }

    // variational layers: 6x RY(qw[lay][q]) then CNOT ring
    #pragma unroll
    for (int lay = 0; lay < 3; ++lay) {
        #pragma unroll
        for (int q = 0; q < 6; ++q) {
            const int m = 1 << (5 - q);
            const float c = __shfl(ca, 6 + lay * 6 + q);
            const float s = __shfl(sa, 6 + lay * 6 + q);
            const float sg = (l & m) ? s : -s;
            const float pr = __shfl_xor(re, m), pi = __shfl_xor(im, m);
            const float nr = c * re + sg * pr;
            const float ni = c * im + sg * pi;
            re = nr; im = ni;
        }
        re = __shfl(re, src);
        im = __shfl(im, src);
    }

    // probabilities -> Walsh-Hadamard: lane L ends with sum_s (-1)^{pop(L&s)} p_s
    float p = re * re + im * im;
    #pragma unroll
    for (int k = 0; k < 6; ++k) {
        const int m = 1 << k;
        const float t = __shfl_xor(p, m);
        p = (l & m) ? (t - p) : (t + p);
    }
    // q[j] sits at lane 32>>j ; gather to lanes 0..5 and publish to LDS
    const int srcl = (l < 6) ? (32 >> l) : 0;
    const float v = __shfl(p, srcl);
    if (l < 6) q6s[wv][l] = v;
    __syncthreads();

    // ---- phase 2: epilogue  out = hx + q6 @ fc_w^T + fc_b ----
    floatx4* out4 = (floatx4*)out;
    #pragma unroll
    for (int k = 0; k < 4; ++k) {
        const float* qb = q6s[k];
        const float q0 = qb[0], q1 = qb[1], q2 = qb[2];
        const float q3 = qb[3], q4 = qb[4], q5 = qb[5];
        const float4 hvk = (k == 0) ? hv0 : (k == 1) ? hv1 : (k == 2) ? hv2 : hv3;
        floatx4 res;
        res.x = hvk.x + bv.x + q0*a0.x + q1*a0.y + q2*a0.z + q3*a0.w + q4*a1.x + q5*a1.y;
        res.y = hvk.y + bv.y + q0*a1.z + q1*a1.w + q2*a2.x + q3*a2.y + q4*a2.z + q5*a2.w;
        res.z = hvk.z + bv.z + q0*a3.x + q1*a3.y + q2*a3.z + q3*a3.w + q4*a4.x + q5*a4.y;
        res.w = hvk.w + bv.w + q0*a4.z + q1*a4.w + q2*a5.x + q3*a5.y + q4*a5.z + q5*a5.w;
        __builtin_nontemporal_store(res, &out4[(size_t)(bid + k * G) * 256 + tid]);
    }
}

extern "C" void kernel_launch(void* const* d_in, const int* in_sizes, int n_in,
                              void* d_out, int out_size, void* d_ws, size_t ws_size,
                              hipStream_t stream) {
    const float* x    = (const float*)d_in[0];   // (B, 6)
    const float* hx   = (const float*)d_in[1];   // (B, H)
    const float* qw   = (const float*)d_in[2];   // (3, 6)
    const float* fc_w = (const float*)d_in[3];   // (H, 6)
    const float* fc_b = (const float*)d_in[4];   // (H,)
    float* out = (float*)d_out;

    const int B = in_sizes[0] / NQ;              // 32768
    // H fixed at 1024 (kernel hardcodes 256 float4 per row)

    // 4 rows per block (one per wave); rows bid + k*G, G = B/4 = 8192 blocks
    qrnn_fused_kernel<<<B / 4, 256, 0, stream>>>(x, hx, qw, fc_w, fc_b, out);
}